// Round 5
// baseline (713.063 us; speedup 1.0000x reference)
//
#include <hip/hip_runtime.h>
#include <cstdint>
#include <cstddef>

typedef unsigned short u16;

#define HH 256
#define IIN 128
#define TT 512
#define G3 768

typedef __attribute__((ext_vector_type(8))) short bf16x8;
typedef __attribute__((ext_vector_type(4))) float f32x4;
typedef __attribute__((ext_vector_type(4))) int   i32x4;

__device__ __forceinline__ u16 f2bf(float f) {
    union { float f; uint32_t i; } c; c.f = f;
    uint32_t r = c.i + 0x7fffu + ((c.i >> 16) & 1u);
    return (u16)(r >> 16);
}
__device__ __forceinline__ float bf2f(u16 s) {
    union { uint32_t i; float f; } u; u.i = ((uint32_t)s) << 16; return u.f;
}
__device__ __forceinline__ float frcp(float x) { return __builtin_amdgcn_rcpf(x); }
__device__ __forceinline__ float sigm(float x) {
    float e = __expf(-fabsf(x));
    float s = frcp(1.f + e);
    return x >= 0.f ? s : 1.f - s;   // 1-s == e/(1+e)
}
__device__ __forceinline__ float tanh_f(float x) {
    float e = __expf(-2.f * fabsf(x));          // overflow-safe
    float t = (1.f - e) * frcp(1.f + e);
    return x >= 0.f ? t : -t;
}

// lgkmcnt-only barrier: drains LDS ops for cross-wave visibility but leaves
// global (vmcnt) loads in flight.
#define LDS_BARRIER() asm volatile("s_waitcnt lgkmcnt(0)\n\ts_barrier" ::: "memory")

// ---------------------------------------------------------------------------
// Kernel 1 v3: xg[m][g] = x_row(m) . W_ih[g] + b_ih[g] + (g<512 ? b_hh[g] : 0)
// v1 (206us) and v2 (189us) were insensitive to 8x traffic reduction ->
// stall-bound, not BW-bound. v2's structure: 1 wave/SIMD + a barrier+
// LDS-stage serialization per x-tile. v3 removes it:
//  - W (3 x 128-col tiles, 104 KB) staged to LDS ONCE; one barrier total.
//  - x loaded global->register A-fragments (identical (quad,byte)->k map
//    as the LDS path, so MFMA semantics unchanged); NO barriers in loop.
//  - 512 threads = 8 waves = 2 waves/SIMD; waves free-run, load latency
//    hides under the other wave's MFMA/stores.
// ---------------------------------------------------------------------------
__global__ __launch_bounds__(512, 1) void xg_gemm(
    const float* __restrict__ x, const float* __restrict__ W_ih,
    const float* __restrict__ b_ih, const float* __restrict__ b_hh,
    u16* __restrict__ xg, int t0, int lt)
{
    // stride 136 u16 = 272B (odd multiple of 16B) -> conflict-free b128 reads
    __shared__ u16 wB[3][128 * 136];
    __shared__ float biasS[384];
    const int tid = threadIdx.x;
    const int TcM = (1 << lt) - 1;
    const int lane = tid & 63, wv = tid >> 6;       // wv in [0,8)
    const int quad = lane >> 4, colL = lane & 15;
    const int srow = tid >> 5, sc = (tid & 31) * 4; // 16 rows/pass, 8 passes

    // ---- stage 3 W-tiles (this block's 384 cols) once ----
    #pragma unroll
    for (int w3 = 0; w3 < 3; ++w3) {
        const int n0 = blockIdx.y * 384 + w3 * 128;
        #pragma unroll
        for (int it = 0; it < 8; ++it) {
            int r = srow + it * 16;
            float4 wv4 = *(const float4*)(W_ih + (size_t)(n0 + r) * IIN + sc);
            ushort4 ws4 = { f2bf(wv4.x), f2bf(wv4.y), f2bf(wv4.z), f2bf(wv4.w) };
            *(ushort4*)&wB[w3][r * 136 + sc] = ws4;
        }
    }
    if (tid < 384) {
        int g = blockIdx.y * 384 + tid;
        float bv = b_ih[g];
        if (g < 512) bv += b_hh[g];     // fold b_hh into r,z pre-activations
        biasS[tid] = bv;
    }
    __syncthreads();                    // the only barrier

    const int colbase = blockIdx.y * 384;

    // ---- 4 passes x 256 rows (wave wv owns rows [wv*32, wv*32+32)) ----
    for (int p = 0; p < 4; ++p) {
        const int mrow = blockIdx.x * 1024 + p * 256 + wv * 32;

        // x -> A fragments in registers (no LDS, no sync)
        bf16x8 A[2][4];
        #pragma unroll
        for (int i = 0; i < 2; ++i) {
            int row = mrow + i * 16 + colL;
            int b = row >> lt;
            int t = t0 + (row & TcM);
            const float* xr = x + ((size_t)b * TT + t) * IIN;
            #pragma unroll
            for (int kt = 0; kt < 4; ++kt) {
                float4 lo = *(const float4*)(xr + kt * 32 + quad * 8);
                float4 hi = *(const float4*)(xr + kt * 32 + quad * 8 + 4);
                union { bf16x8 v; u16 s[8]; } u;
                u.s[0] = f2bf(lo.x); u.s[1] = f2bf(lo.y);
                u.s[2] = f2bf(lo.z); u.s[3] = f2bf(lo.w);
                u.s[4] = f2bf(hi.x); u.s[5] = f2bf(hi.y);
                u.s[6] = f2bf(hi.z); u.s[7] = f2bf(hi.w);
                A[i][kt] = u.v;
            }
        }

        #pragma unroll
        for (int w3 = 0; w3 < 3; ++w3) {
            f32x4 C[2][8] = {};
            #pragma unroll
            for (int kt = 0; kt < 4; ++kt)
                #pragma unroll
                for (int nn = 0; nn < 8; ++nn) {
                    bf16x8 Bf = *(const bf16x8*)&wB[w3][(nn * 16 + colL) * 136 + kt * 32 + quad * 8];
                    C[0][nn] = __builtin_amdgcn_mfma_f32_16x16x32_bf16(A[0][kt], Bf, C[0][nn], 0, 0, 0);
                    C[1][nn] = __builtin_amdgcn_mfma_f32_16x16x32_bf16(A[1][kt], Bf, C[1][nn], 0, 0, 0);
                }
            // C layout [m89]: row = quad*4 + reg, col = lane&15
            #pragma unroll
            for (int i = 0; i < 2; ++i)
                #pragma unroll
                for (int nn = 0; nn < 8; ++nn) {
                    int cl = w3 * 128 + nn * 16 + colL;
                    float bv = biasS[cl];
                    #pragma unroll
                    for (int r = 0; r < 4; ++r) {
                        int row = mrow + i * 16 + quad * 4 + r;
                        xg[(size_t)row * G3 + colbase + cl] = f2bf(C[i][nn][r] + bv);
                    }
                }
        }
    }
}

// ---------------------------------------------------------------------------
// Kernel 2 (unchanged, passing @~510us): persistent per-batch recurrence.
// grid=256, block=512 (8 waves, 2/SIMD). i8 K=64 MFMAs for r,z (sigmoid
// slope <=0.25 damps quant noise); n gate (integrator) in bf16.
// Per-CU MFMA floor ~1274 cyc/step; measured ~2390 -> tail is the next
// lever (i8 n-gate or sync-structure change -- kept decoupled from this
// round's xg change).
// ---------------------------------------------------------------------------
#define GRU_STEP(TC_, HBR_, HBW_, HQR_, HQW_, PR_, PZ_, PN_) do {              \
    f32x4 Cn[2] = {};                                                          \
    i32x4 Cr[2] = {}, Cz[2] = {};                                              \
    _Pragma("unroll")                                                          \
    for (int kt = 0; kt < 4; ++kt) {                                           \
        i32x4 Aq = *(const i32x4*)((const char*)(HQR_) + kt * 64 + quad * 16); \
        Cr[0] = __builtin_amdgcn_mfma_i32_16x16x64_i8(Aq, Br[0][kt], Cr[0], 0, 0, 0); \
        Cr[1] = __builtin_amdgcn_mfma_i32_16x16x64_i8(Aq, Br[1][kt], Cr[1], 0, 0, 0); \
        Cz[0] = __builtin_amdgcn_mfma_i32_16x16x64_i8(Aq, Bz[0][kt], Cz[0], 0, 0, 0); \
        Cz[1] = __builtin_amdgcn_mfma_i32_16x16x64_i8(Aq, Bz[1][kt], Cz[1], 0, 0, 0); \
    }                                                                          \
    _Pragma("unroll")                                                          \
    for (int kt = 0; kt < 8; ++kt) {                                           \
        bf16x8 A = *(const bf16x8*)&HBR_[kt * 32 + quad * 8];                  \
        Cn[0] = __builtin_amdgcn_mfma_f32_16x16x32_bf16(A, Bn[0][kt], Cn[0], 0, 0, 0); \
        Cn[1] = __builtin_amdgcn_mfma_f32_16x16x32_bf16(A, Bn[1][kt], Cn[1], 0, 0, 0); \
    }                                                                          \
    float dr = (float)(i16 ? Cr[1][0] : Cr[0][0]) * scR;                       \
    float dz = (float)(i16 ? Cz[1][0] : Cz[0][0]) * scZ;                       \
    float dn = i16 ? Cn[1][0] : Cn[0][0];                                      \
    float xr = PR_, xz = PZ_, xn = PN_;                                        \
    int t2 = (TC_) + 2; if (t2 > Tc - 1) t2 = Tc - 1;                          \
    const u16* p2 = xgb + (size_t)t2 * G3;                                     \
    PR_ = bf2f(p2[j]); PZ_ = bf2f(p2[256 + j]); PN_ = bf2f(p2[512 + j]);       \
    float r = sigm(xr + dr);                                                   \
    float z = sigm(xz + dz);                                                   \
    float n = tanh_f(xn + r * (dn + bhn));                                     \
    hreg = n + z * (hreg - n);                                                 \
    float hc = fminf(fmaxf(hreg, -1.f), 1.f);   /* |h|<=1 mathematically */    \
    int hq8 = (int)rintf(hc * 127.f);                                          \
    if (lane < 32) {                                                           \
        HBW_[j] = f2bf(hreg);                                                  \
        ((char*)(HQW_))[j] = (char)hq8;                                        \
        outb[(size_t)(t0 + (TC_)) * HH + j] = hreg;                            \
    }                                                                          \
    LDS_BARRIER();                                                             \
} while (0)

__global__ __launch_bounds__(512, 1) void gru_seq(
    const float* __restrict__ W_hh, const float* __restrict__ b_hh,
    const u16* __restrict__ xg, float* __restrict__ out,
    float* __restrict__ hstate, int t0, int Tc)
{
    __shared__ __align__(16) u16 hBuf[2][HH];   // h bf16, double-buffered (n gate)
    __shared__ __align__(16) int hqBuf[2][HH / 4]; // h int8 (*127), double-buffered (r,z)

    const int tid = threadIdx.x;
    const int lane = tid & 63, wv = tid >> 6;       // wv in [0,8)
    const int quad = lane >> 4, colL = lane & 15;
    const int i16 = quad & 1;                       // which 16-col tile
    const int j = wv * 32 + (lane & 31);            // hidden index this lane owns
    const int b = blockIdx.x;

    // ---- n-gate weights: bf16 fragments (rows 512..767) ----
    bf16x8 Bn[2][8];
    #pragma unroll
    for (int i = 0; i < 2; ++i) {
        const size_t rowb = (size_t)(512 + wv * 32 + i * 16 + colL) * HH;
        #pragma unroll
        for (int kt = 0; kt < 8; ++kt) {
            float4 lo = *(const float4*)(W_hh + rowb + kt * 32 + quad * 8);
            float4 hi = *(const float4*)(W_hh + rowb + kt * 32 + quad * 8 + 4);
            union { bf16x8 v; u16 s[8]; } u;
            u.s[0] = f2bf(lo.x); u.s[1] = f2bf(lo.y);
            u.s[2] = f2bf(lo.z); u.s[3] = f2bf(lo.w);
            u.s[4] = f2bf(hi.x); u.s[5] = f2bf(hi.y);
            u.s[6] = f2bf(hi.z); u.s[7] = f2bf(hi.w);
            Bn[i][kt] = u.v;
        }
    }

    // ---- r,z weights: per-row-scaled int8, packed 16 bytes/frag ----
    i32x4 Br[2][4], Bz[2][4];
    float scR = 0.f, scZ = 0.f;     // combined dequant scale rowmax/(127*127)
    #pragma unroll
    for (int g = 0; g < 2; ++g) {
        #pragma unroll
        for (int i = 0; i < 2; ++i) {
            const float* wr = W_hh + (size_t)(g * 256 + wv * 32 + i * 16 + colL) * HH;
            float m = 0.f;
            #pragma unroll
            for (int kt = 0; kt < 4; ++kt)
                #pragma unroll
                for (int u4 = 0; u4 < 4; ++u4) {
                    float4 v = *(const float4*)(wr + kt * 64 + quad * 16 + u4 * 4);
                    m = fmaxf(m, fmaxf(fmaxf(fabsf(v.x), fabsf(v.y)),
                                       fmaxf(fabsf(v.z), fabsf(v.w))));
                }
            m = fmaxf(m, __shfl_xor(m, 16));    // full row spans all 4 quads
            m = fmaxf(m, __shfl_xor(m, 32));
            float inv = m > 1e-30f ? 127.f / m : 0.f;
            float sc  = m * (1.f / 16129.f);
            #pragma unroll
            for (int kt = 0; kt < 4; ++kt) {
                int pk[4];
                #pragma unroll
                for (int u4 = 0; u4 < 4; ++u4) {
                    float4 v = *(const float4*)(wr + kt * 64 + quad * 16 + u4 * 4);
                    int q0 = (int)rintf(fminf(fmaxf(v.x * inv, -127.f), 127.f));
                    int q1 = (int)rintf(fminf(fmaxf(v.y * inv, -127.f), 127.f));
                    int q2 = (int)rintf(fminf(fmaxf(v.z * inv, -127.f), 127.f));
                    int q3 = (int)rintf(fminf(fmaxf(v.w * inv, -127.f), 127.f));
                    pk[u4] = (q0 & 255) | ((q1 & 255) << 8) | ((q2 & 255) << 16) | (q3 << 24);
                }
                i32x4 t = { pk[0], pk[1], pk[2], pk[3] };
                if (g == 0) Br[i][kt] = t; else Bz[i][kt] = t;
            }
            if (i == i16) { if (g == 0) scR = sc; else scZ = sc; }
        }
    }

    float hreg = (t0 == 0) ? 0.f : hstate[b * HH + j];
    if (lane < 32) {
        hBuf[0][j] = f2bf(hreg);
        float hc = fminf(fmaxf(hreg, -1.f), 1.f);
        ((char*)hqBuf[0])[j] = (char)(int)rintf(hc * 127.f);
    }
    const float bhn = b_hh[512 + j];
    const u16* xgb = xg + (size_t)b * Tc * G3;
    float* outb = out + (size_t)b * TT * HH;

    // 2-deep xg prefetch (upper half-wave duplicates lower -> same cachelines)
    float pr0 = bf2f(xgb[j]),      pz0 = bf2f(xgb[256 + j]),      pn0 = bf2f(xgb[512 + j]);
    float pr1 = bf2f(xgb[G3 + j]), pz1 = bf2f(xgb[G3 + 256 + j]), pn1 = bf2f(xgb[G3 + 512 + j]);
    __syncthreads();   // once: weight/h init visible

    for (int tc = 0; tc < Tc; tc += 2) {
        GRU_STEP(tc,     hBuf[0], hBuf[1], hqBuf[0], hqBuf[1], pr0, pz0, pn0);
        GRU_STEP(tc + 1, hBuf[1], hBuf[0], hqBuf[1], hqBuf[0], pr1, pz1, pn1);
    }

    if (t0 + Tc < TT && lane < 32)      // only needed across chunks
        hstate[b * HH + j] = hreg;
}

extern "C" void kernel_launch(void* const* d_in, const int* in_sizes, int n_in,
                              void* d_out, int out_size, void* d_ws, size_t ws_size,
                              hipStream_t stream) {
    const float* x    = (const float*)d_in[0];
    const float* W_ih = (const float*)d_in[1];
    const float* W_hh = (const float*)d_in[2];
    const float* b_ih = (const float*)d_in[3];
    const float* b_hh = (const float*)d_in[4];
    float* out = (float*)d_out;                    // fp32 output [B,T,H]

    float* hstate = (float*)d_ws;                  // 256*256 fp32 = 256 KB
    u16* xg = (u16*)((char*)d_ws + 262144);        // [256*Tc, 768] bf16
    size_t avail = ws_size > 262144 ? ws_size - 262144 : 0;

    int Tc = TT, lt = 9;                           // shrink chunk to fit ws
    while (Tc > 4 && (size_t)256 * Tc * G3 * 2 > avail) { Tc >>= 1; --lt; }

    for (int t0 = 0; t0 < TT; t0 += Tc) {
        // rows = 256*Tc, 1024 rows/block -> grid.x = Tc/4; grid.y = 2 (384 cols each)
        xg_gemm<<<dim3(Tc / 4, 2), 512, 0, stream>>>(
            x, W_ih, b_ih, b_hh, xg, t0, lt);
        gru_seq<<<dim3(256), 512, 0, stream>>>(
            W_hh, b_hh, xg, out, hstate, t0, Tc);
    }
}

// Round 7
// 682.006 us; speedup vs baseline: 1.0455x; 1.0455x over previous
//
#include <hip/hip_runtime.h>
#include <cstdint>
#include <cstddef>

typedef unsigned short u16;

#define HH 256
#define IIN 128
#define TT 512
#define G3 768

typedef __attribute__((ext_vector_type(8))) short bf16x8;
typedef __attribute__((ext_vector_type(4))) float f32x4;
typedef __attribute__((ext_vector_type(4))) int   i32x4;

__device__ __forceinline__ u16 f2bf(float f) {
    union { float f; uint32_t i; } c; c.f = f;
    uint32_t r = c.i + 0x7fffu + ((c.i >> 16) & 1u);
    return (u16)(r >> 16);
}
__device__ __forceinline__ float bf2f(u16 s) {
    union { uint32_t i; float f; } u; u.i = ((uint32_t)s) << 16; return u.f;
}
__device__ __forceinline__ float frcp(float x) { return __builtin_amdgcn_rcpf(x); }
__device__ __forceinline__ float sigm(float x) {
    float e = __expf(-fabsf(x));
    float s = frcp(1.f + e);
    return x >= 0.f ? s : 1.f - s;   // 1-s == e/(1+e)
}
__device__ __forceinline__ float tanh_f(float x) {
    float e = __expf(-2.f * fabsf(x));          // overflow-safe
    float t = (1.f - e) * frcp(1.f + e);
    return x >= 0.f ? t : -t;
}

// lgkmcnt-only barrier: drains LDS ops for cross-wave visibility but leaves
// global (vmcnt) loads in flight.
#define LDS_BARRIER() asm volatile("s_waitcnt lgkmcnt(0)\n\ts_barrier" ::: "memory")

// ---------------------------------------------------------------------------
// FUSED kernel. grid=256 (block b owns batch b end-to-end), block=512.
//
// The standalone xg GEMM cost a ~190us residual that was INVARIANT to fp32->
// bf16 output, 8x W-traffic cut, and barrier removal (rounds 2-5) -- i.e. it
// was dominated by per-dispatch/serialization overhead, not GEMM work
// (bottom-up floor ~60us). There is no cross-block dependency (block b needs
// only x[b] and W_ih), so the GEMM fuses in as phase 1:
//   phase 1: x[b] (Tc x 128) staged once to LDS (stride-136 bf16, conflict-
//            free); W_ih as per-wave register B-frags (wave owns 96 cols);
//            zero barriers in the M-loop; scalar u16 stores (L2 merges
//            partial lines). Same kt accumulation order as the old kernel ->
//            bitwise-identical xg.
//   phase 2: vmcnt(0) + __syncthreads (stores visible via L2; L1 is
//            invalidated at dispatch, and these lines were never read
//            earlier in the launch) -> byte-identical recurrence.
// ---------------------------------------------------------------------------
#define GRU_STEP(TC_, HBR_, HBW_, HQR_, HQW_, PR_, PZ_, PN_) do {              \
    f32x4 Cn[2] = {};                                                          \
    i32x4 Cr[2] = {}, Cz[2] = {};                                              \
    _Pragma("unroll")                                                          \
    for (int kt = 0; kt < 4; ++kt) {                                           \
        i32x4 Aq = *(const i32x4*)((const char*)(HQR_) + kt * 64 + quad * 16); \
        Cr[0] = __builtin_amdgcn_mfma_i32_16x16x64_i8(Aq, Br[0][kt], Cr[0], 0, 0, 0); \
        Cr[1] = __builtin_amdgcn_mfma_i32_16x16x64_i8(Aq, Br[1][kt], Cr[1], 0, 0, 0); \
        Cz[0] = __builtin_amdgcn_mfma_i32_16x16x64_i8(Aq, Bz[0][kt], Cz[0], 0, 0, 0); \
        Cz[1] = __builtin_amdgcn_mfma_i32_16x16x64_i8(Aq, Bz[1][kt], Cz[1], 0, 0, 0); \
    }                                                                          \
    _Pragma("unroll")                                                          \
    for (int kt = 0; kt < 8; ++kt) {                                           \
        bf16x8 A = *(const bf16x8*)&HBR_[kt * 32 + quad * 8];                  \
        Cn[0] = __builtin_amdgcn_mfma_f32_16x16x32_bf16(A, Bn[0][kt], Cn[0], 0, 0, 0); \
        Cn[1] = __builtin_amdgcn_mfma_f32_16x16x32_bf16(A, Bn[1][kt], Cn[1], 0, 0, 0); \
    }                                                                          \
    float dr = (float)(i16 ? Cr[1][0] : Cr[0][0]) * scR;                       \
    float dz = (float)(i16 ? Cz[1][0] : Cz[0][0]) * scZ;                       \
    float dn = i16 ? Cn[1][0] : Cn[0][0];                                      \
    float xr = PR_, xz = PZ_, xn = PN_;                                        \
    int t2 = (TC_) + 2; if (t2 > Tc - 1) t2 = Tc - 1;                          \
    const u16* p2 = xgb + (size_t)t2 * G3;                                     \
    PR_ = bf2f(p2[j]); PZ_ = bf2f(p2[256 + j]); PN_ = bf2f(p2[512 + j]);       \
    float r = sigm(xr + dr);                                                   \
    float z = sigm(xz + dz);                                                   \
    float n = tanh_f(xn + r * (dn + bhn));                                     \
    hreg = n + z * (hreg - n);                                                 \
    float hc = fminf(fmaxf(hreg, -1.f), 1.f);   /* |h|<=1 mathematically */    \
    int hq8 = (int)rintf(hc * 127.f);                                          \
    if (lane < 32) {                                                           \
        HBW_[j] = f2bf(hreg);                                                  \
        ((char*)(HQW_))[j] = (char)hq8;                                        \
        outb[(size_t)(t0 + (TC_)) * HH + j] = hreg;                            \
    }                                                                          \
    LDS_BARRIER();                                                             \
} while (0)

__global__ __launch_bounds__(512, 1) void gru_fused(
    const float* __restrict__ x, const float* __restrict__ W_ih,
    const float* __restrict__ W_hh,
    const float* __restrict__ b_ih, const float* __restrict__ b_hh,
    u16* __restrict__ xg, float* __restrict__ out,
    float* __restrict__ hstate, int t0, int Tc)
{
    // phase 1: x[b] bf16, stride 136 u16 (272B, odd multiple of 16B ->
    // conflict-free b128 reads). 512*136*2 = 139264 B.
    __shared__ u16 xS[TT * 136];
    // phase 2 buffers (disjoint lifetime, but they all fit: ~140.5 KB total)
    __shared__ __align__(16) u16 hBuf[2][HH];      // h bf16, double-buffered
    __shared__ __align__(16) int hqBuf[2][HH / 4]; // h int8 (*127), dbuf

    const int tid = threadIdx.x;
    const int lane = tid & 63, wv = tid >> 6;       // wv in [0,8)
    const int quad = lane >> 4, colL = lane & 15;
    const int i16 = quad & 1;                       // which 16-col tile
    const int j = wv * 32 + (lane & 31);            // hidden index (phase 2)
    const int b = blockIdx.x;

    u16* xgw = xg + (size_t)b * Tc * G3;

    // =========================== phase 1: xg ================================
    {
        // stage x[b] rows [t0, t0+Tc) -> bf16 LDS (coalesced float4)
        for (int idx = tid; idx < Tc * 32; idx += 512) {
            int r = idx >> 5, c4 = (idx & 31) * 4;
            float4 xv = *(const float4*)(x + ((size_t)b * TT + t0 + r) * IIN + c4);
            ushort4 xs = { f2bf(xv.x), f2bf(xv.y), f2bf(xv.z), f2bf(xv.w) };
            *(ushort4*)&xS[r * 136 + c4] = xs;
        }
        // W_ih -> per-wave register B-frags: wave owns cols [wv*96, wv*96+96)
        bf16x8 Bi[6][4];
        float bvv[6];
        #pragma unroll
        for (int n = 0; n < 6; ++n) {
            int col = wv * 96 + n * 16 + colL;
            const float* wr = W_ih + (size_t)col * IIN;
            #pragma unroll
            for (int kt = 0; kt < 4; ++kt) {
                float4 lo = *(const float4*)(wr + kt * 32 + quad * 8);
                float4 hi = *(const float4*)(wr + kt * 32 + quad * 8 + 4);
                union { bf16x8 v; u16 s[8]; } u;
                u.s[0] = f2bf(lo.x); u.s[1] = f2bf(lo.y);
                u.s[2] = f2bf(lo.z); u.s[3] = f2bf(lo.w);
                u.s[4] = f2bf(hi.x); u.s[5] = f2bf(hi.y);
                u.s[6] = f2bf(hi.z); u.s[7] = f2bf(hi.w);
                Bi[n][kt] = u.v;
            }
            float bv = b_ih[col];
            if (col < 512) bv += b_hh[col];     // fold b_hh into r,z pre-acts
            bvv[n] = bv;
        }
        __syncthreads();                        // xS ready

        // every wave sweeps ALL M-tiles for its 96 cols; no barriers
        for (int mt = 0; mt < Tc / 16; ++mt) {
            bf16x8 A[4];
            #pragma unroll
            for (int kt = 0; kt < 4; ++kt)
                A[kt] = *(const bf16x8*)&xS[(mt * 16 + colL) * 136 + kt * 32 + quad * 8];
            f32x4 C[6] = {};
            #pragma unroll
            for (int kt = 0; kt < 4; ++kt)
                #pragma unroll
                for (int n = 0; n < 6; ++n)
                    C[n] = __builtin_amdgcn_mfma_f32_16x16x32_bf16(A[kt], Bi[n][kt], C[n], 0, 0, 0);
            // C layout [m89]: row = quad*4 + reg, col = lane&15
            #pragma unroll
            for (int n = 0; n < 6; ++n) {
                int col = wv * 96 + n * 16 + colL;
                #pragma unroll
                for (int r = 0; r < 4; ++r) {
                    int tt = mt * 16 + quad * 4 + r;
                    xgw[(size_t)tt * G3 + col] = f2bf(C[n][r] + bvv[n]);
                }
            }
        }
        // all xg stores to L2 before any wave's phase-2 reads
        asm volatile("s_waitcnt vmcnt(0)" ::: "memory");
        __syncthreads();
    }

    // ========================= phase 2: recurrence ==========================
    // ---- n-gate weights: bf16 fragments (rows 512..767) ----
    bf16x8 Bn[2][8];
    #pragma unroll
    for (int i = 0; i < 2; ++i) {
        const size_t rowb = (size_t)(512 + wv * 32 + i * 16 + colL) * HH;
        #pragma unroll
        for (int kt = 0; kt < 8; ++kt) {
            float4 lo = *(const float4*)(W_hh + rowb + kt * 32 + quad * 8);
            float4 hi = *(const float4*)(W_hh + rowb + kt * 32 + quad * 8 + 4);
            union { bf16x8 v; u16 s[8]; } u;
            u.s[0] = f2bf(lo.x); u.s[1] = f2bf(lo.y);
            u.s[2] = f2bf(lo.z); u.s[3] = f2bf(lo.w);
            u.s[4] = f2bf(hi.x); u.s[5] = f2bf(hi.y);
            u.s[6] = f2bf(hi.z); u.s[7] = f2bf(hi.w);
            Bn[i][kt] = u.v;
        }
    }

    // ---- r,z weights: per-row-scaled int8, packed 16 bytes/frag ----
    i32x4 Br[2][4], Bz[2][4];
    float scR = 0.f, scZ = 0.f;     // combined dequant scale rowmax/(127*127)
    #pragma unroll
    for (int g = 0; g < 2; ++g) {
        #pragma unroll
        for (int i = 0; i < 2; ++i) {
            const float* wr = W_hh + (size_t)(g * 256 + wv * 32 + i * 16 + colL) * HH;
            float m = 0.f;
            #pragma unroll
            for (int kt = 0; kt < 4; ++kt)
                #pragma unroll
                for (int u4 = 0; u4 < 4; ++u4) {
                    float4 v = *(const float4*)(wr + kt * 64 + quad * 16 + u4 * 4);
                    m = fmaxf(m, fmaxf(fmaxf(fabsf(v.x), fabsf(v.y)),
                                       fmaxf(fabsf(v.z), fabsf(v.w))));
                }
            m = fmaxf(m, __shfl_xor(m, 16));    // full row spans all 4 quads
            m = fmaxf(m, __shfl_xor(m, 32));
            float inv = m > 1e-30f ? 127.f / m : 0.f;
            float sc  = m * (1.f / 16129.f);
            #pragma unroll
            for (int kt = 0; kt < 4; ++kt) {
                int pk[4];
                #pragma unroll
                for (int u4 = 0; u4 < 4; ++u4) {
                    float4 v = *(const float4*)(wr + kt * 64 + quad * 16 + u4 * 4);
                    int q0 = (int)rintf(fminf(fmaxf(v.x * inv, -127.f), 127.f));
                    int q1 = (int)rintf(fminf(fmaxf(v.y * inv, -127.f), 127.f));
                    int q2 = (int)rintf(fminf(fmaxf(v.z * inv, -127.f), 127.f));
                    int q3 = (int)rintf(fminf(fmaxf(v.w * inv, -127.f), 127.f));
                    pk[u4] = (q0 & 255) | ((q1 & 255) << 8) | ((q2 & 255) << 16) | (q3 << 24);
                }
                i32x4 t = { pk[0], pk[1], pk[2], pk[3] };
                if (g == 0) Br[i][kt] = t; else Bz[i][kt] = t;
            }
            if (i == i16) { if (g == 0) scR = sc; else scZ = sc; }
        }
    }

    float hreg = (t0 == 0) ? 0.f : hstate[b * HH + j];
    if (lane < 32) {
        hBuf[0][j] = f2bf(hreg);
        float hc = fminf(fmaxf(hreg, -1.f), 1.f);
        ((char*)hqBuf[0])[j] = (char)(int)rintf(hc * 127.f);
    }
    const float bhn = b_hh[512 + j];
    const u16* xgb = xgw;
    float* outb = out + (size_t)b * TT * HH;

    // 2-deep xg prefetch (upper half-wave duplicates lower -> same cachelines)
    float pr0 = bf2f(xgb[j]),      pz0 = bf2f(xgb[256 + j]),      pn0 = bf2f(xgb[512 + j]);
    float pr1 = bf2f(xgb[G3 + j]), pz1 = bf2f(xgb[G3 + 256 + j]), pn1 = bf2f(xgb[G3 + 512 + j]);
    __syncthreads();   // once: weight/h init visible

    for (int tc = 0; tc < Tc; tc += 2) {
        GRU_STEP(tc,     hBuf[0], hBuf[1], hqBuf[0], hqBuf[1], pr0, pz0, pn0);
        GRU_STEP(tc + 1, hBuf[1], hBuf[0], hqBuf[1], hqBuf[0], pr1, pz1, pn1);
    }

    if (t0 + Tc < TT && lane < 32)      // only needed across chunks
        hstate[b * HH + j] = hreg;
}

extern "C" void kernel_launch(void* const* d_in, const int* in_sizes, int n_in,
                              void* d_out, int out_size, void* d_ws, size_t ws_size,
                              hipStream_t stream) {
    const float* x    = (const float*)d_in[0];
    const float* W_ih = (const float*)d_in[1];
    const float* W_hh = (const float*)d_in[2];
    const float* b_ih = (const float*)d_in[3];
    const float* b_hh = (const float*)d_in[4];
    float* out = (float*)d_out;                    // fp32 output [B,T,H]

    float* hstate = (float*)d_ws;                  // 256*256 fp32 = 256 KB
    u16* xg = (u16*)((char*)d_ws + 262144);        // [256*Tc, 768] bf16
    size_t avail = ws_size > 262144 ? ws_size - 262144 : 0;

    int Tc = TT;                                   // shrink chunk to fit ws
    while (Tc > 16 && (size_t)256 * Tc * G3 * 2 > avail) Tc >>= 1;

    for (int t0 = 0; t0 < TT; t0 += Tc) {
        gru_fused<<<dim3(256), 512, 0, stream>>>(
            x, W_ih, W_hh, b_ih, b_hh, xg, out, hstate, t0, Tc);
    }
}

// Round 8
// 607.906 us; speedup vs baseline: 1.1730x; 1.1219x over previous
//
#include <hip/hip_runtime.h>
#include <cstdint>
#include <cstddef>

typedef unsigned short u16;

#define HH 256
#define IIN 128
#define TT 512
#define G3 768

typedef __attribute__((ext_vector_type(8))) short bf16x8;
typedef __attribute__((ext_vector_type(4))) float f32x4;
typedef __attribute__((ext_vector_type(4))) int   i32x4;

__device__ __forceinline__ u16 f2bf(float f) {
    union { float f; uint32_t i; } c; c.f = f;
    uint32_t r = c.i + 0x7fffu + ((c.i >> 16) & 1u);
    return (u16)(r >> 16);
}
__device__ __forceinline__ float bf2f(u16 s) {
    union { uint32_t i; float f; } u; u.i = ((uint32_t)s) << 16; return u.f;
}
__device__ __forceinline__ float frcp(float x) { return __builtin_amdgcn_rcpf(x); }
__device__ __forceinline__ float sigm(float x) {
    float e = __expf(-fabsf(x));
    float s = frcp(1.f + e);
    return x >= 0.f ? s : 1.f - s;   // 1-s == e/(1+e)
}
__device__ __forceinline__ float tanh_f(float x) {
    float e = __expf(-2.f * fabsf(x));          // overflow-safe
    float t = (1.f - e) * frcp(1.f + e);
    return x >= 0.f ? t : -t;
}

// lgkmcnt-only barrier: drains LDS ops for cross-wave visibility but leaves
// global (vmcnt) loads in flight.
#define LDS_BARRIER() asm volatile("s_waitcnt lgkmcnt(0)\n\ts_barrier" ::: "memory")

// ---------------------------------------------------------------------------
// FUSED kernel. grid=256 (block b owns batch b end-to-end), block=512.
// Fusion (round 6) proved the ~190us xg residual was dispatch overhead:
// phase 1 costs ~68us in-kernel (== its traffic floor).
//
// Round 7 change: ALL-i8 recurrence. r,z i8 cost +0.001 absmax (r2);
// n-gate uses the same per-row-scaled i8 weights + the SAME i8 h fragments
// (h-i8 err 0.0039 ~= bf16 ulp near 1; weight err rowmax/254 ~= 2x bf16
// rounding). This:
//   - cuts the MFMA floor 1274 -> 979 cyc/CU/step (24 i8 K=64 MFMAs/wave),
//   - shortens dependent chains (6 chains x 4-deep, sharing 4 Aq reads),
//   - deletes the whole bf16 h path: 8 ds_reads + 1 ds_write + hBuf gone.
// ---------------------------------------------------------------------------
#define GRU_STEP(TC_, HQR_, HQW_, PR_, PZ_, PN_) do {                          \
    i32x4 Cr[2] = {}, Cz[2] = {}, Cn[2] = {};                                  \
    _Pragma("unroll")                                                          \
    for (int kt = 0; kt < 4; ++kt) {                                           \
        i32x4 Aq = *(const i32x4*)((const char*)(HQR_) + kt * 64 + quad * 16); \
        Cr[0] = __builtin_amdgcn_mfma_i32_16x16x64_i8(Aq, Bq[0][0][kt], Cr[0], 0, 0, 0); \
        Cr[1] = __builtin_amdgcn_mfma_i32_16x16x64_i8(Aq, Bq[0][1][kt], Cr[1], 0, 0, 0); \
        Cz[0] = __builtin_amdgcn_mfma_i32_16x16x64_i8(Aq, Bq[1][0][kt], Cz[0], 0, 0, 0); \
        Cz[1] = __builtin_amdgcn_mfma_i32_16x16x64_i8(Aq, Bq[1][1][kt], Cz[1], 0, 0, 0); \
        Cn[0] = __builtin_amdgcn_mfma_i32_16x16x64_i8(Aq, Bq[2][0][kt], Cn[0], 0, 0, 0); \
        Cn[1] = __builtin_amdgcn_mfma_i32_16x16x64_i8(Aq, Bq[2][1][kt], Cn[1], 0, 0, 0); \
    }                                                                          \
    float dr = (float)(i16 ? Cr[1][0] : Cr[0][0]) * scG[0];                    \
    float dz = (float)(i16 ? Cz[1][0] : Cz[0][0]) * scG[1];                    \
    float dn = (float)(i16 ? Cn[1][0] : Cn[0][0]) * scG[2];                    \
    float xr = PR_, xz = PZ_, xn = PN_;                                        \
    int t2 = (TC_) + 2; if (t2 > Tc - 1) t2 = Tc - 1;                          \
    const u16* p2 = xgb + (size_t)t2 * G3;                                     \
    PR_ = bf2f(p2[j]); PZ_ = bf2f(p2[256 + j]); PN_ = bf2f(p2[512 + j]);       \
    float r = sigm(xr + dr);                                                   \
    float z = sigm(xz + dz);                                                   \
    float n = tanh_f(xn + r * (dn + bhn));                                     \
    hreg = n + z * (hreg - n);                                                 \
    float hc = fminf(fmaxf(hreg, -1.f), 1.f);   /* |h|<=1 mathematically */    \
    int hq8 = (int)rintf(hc * 127.f);                                          \
    if (lane < 32) {                                                           \
        ((char*)(HQW_))[j] = (char)hq8;                                        \
        outb[(size_t)(t0 + (TC_)) * HH + j] = hreg;                            \
    }                                                                          \
    LDS_BARRIER();                                                             \
} while (0)

__global__ __launch_bounds__(512, 1) void gru_fused(
    const float* __restrict__ x, const float* __restrict__ W_ih,
    const float* __restrict__ W_hh,
    const float* __restrict__ b_ih, const float* __restrict__ b_hh,
    u16* __restrict__ xg, float* __restrict__ out,
    float* __restrict__ hstate, int t0, int Tc)
{
    // phase 1: x[b] bf16, stride 136 u16 (272B, odd multiple of 16B ->
    // conflict-free b128 reads). 512*136*2 = 139264 B.
    __shared__ u16 xS[TT * 136];
    // phase 2: h int8 (*127), double-buffered. Only cross-wave state.
    __shared__ __align__(16) int hqBuf[2][HH / 4];

    const int tid = threadIdx.x;
    const int lane = tid & 63, wv = tid >> 6;       // wv in [0,8)
    const int quad = lane >> 4, colL = lane & 15;
    const int i16 = quad & 1;                       // which 16-col tile
    const int j = wv * 32 + (lane & 31);            // hidden index (phase 2)
    const int b = blockIdx.x;

    u16* xgw = xg + (size_t)b * Tc * G3;

    // =========================== phase 1: xg ================================
    {
        // stage x[b] rows [t0, t0+Tc) -> bf16 LDS (coalesced float4)
        for (int idx = tid; idx < Tc * 32; idx += 512) {
            int r = idx >> 5, c4 = (idx & 31) * 4;
            float4 xv = *(const float4*)(x + ((size_t)b * TT + t0 + r) * IIN + c4);
            ushort4 xs = { f2bf(xv.x), f2bf(xv.y), f2bf(xv.z), f2bf(xv.w) };
            *(ushort4*)&xS[r * 136 + c4] = xs;
        }
        // W_ih -> per-wave register B-frags: wave owns cols [wv*96, wv*96+96)
        bf16x8 Bi[6][4];
        float bvv[6];
        #pragma unroll
        for (int n = 0; n < 6; ++n) {
            int col = wv * 96 + n * 16 + colL;
            const float* wr = W_ih + (size_t)col * IIN;
            #pragma unroll
            for (int kt = 0; kt < 4; ++kt) {
                float4 lo = *(const float4*)(wr + kt * 32 + quad * 8);
                float4 hi = *(const float4*)(wr + kt * 32 + quad * 8 + 4);
                union { bf16x8 v; u16 s[8]; } u;
                u.s[0] = f2bf(lo.x); u.s[1] = f2bf(lo.y);
                u.s[2] = f2bf(lo.z); u.s[3] = f2bf(lo.w);
                u.s[4] = f2bf(hi.x); u.s[5] = f2bf(hi.y);
                u.s[6] = f2bf(hi.z); u.s[7] = f2bf(hi.w);
                Bi[n][kt] = u.v;
            }
            float bv = b_ih[col];
            if (col < 512) bv += b_hh[col];     // fold b_hh into r,z pre-acts
            bvv[n] = bv;
        }
        __syncthreads();                        // xS ready

        // every wave sweeps ALL M-tiles for its 96 cols; no barriers
        for (int mt = 0; mt < Tc / 16; ++mt) {
            bf16x8 A[4];
            #pragma unroll
            for (int kt = 0; kt < 4; ++kt)
                A[kt] = *(const bf16x8*)&xS[(mt * 16 + colL) * 136 + kt * 32 + quad * 8];
            f32x4 C[6] = {};
            #pragma unroll
            for (int kt = 0; kt < 4; ++kt)
                #pragma unroll
                for (int n = 0; n < 6; ++n)
                    C[n] = __builtin_amdgcn_mfma_f32_16x16x32_bf16(A[kt], Bi[n][kt], C[n], 0, 0, 0);
            // C layout [m89]: row = quad*4 + reg, col = lane&15
            #pragma unroll
            for (int n = 0; n < 6; ++n) {
                int col = wv * 96 + n * 16 + colL;
                #pragma unroll
                for (int r = 0; r < 4; ++r) {
                    int tt = mt * 16 + quad * 4 + r;
                    xgw[(size_t)tt * G3 + col] = f2bf(C[n][r] + bvv[n]);
                }
            }
        }
        // all xg stores to L2 before any wave's phase-2 reads
        asm volatile("s_waitcnt vmcnt(0)" ::: "memory");
        __syncthreads();
    }

    // ========================= phase 2: recurrence ==========================
    // all 3 gates: per-row-scaled int8 weights, packed 16 bytes/frag.
    // frag byte (quad,u*4+e) holds W[row][kt*64 + quad*16 + u*4+e]*127/rowmax
    i32x4 Bq[3][2][4];
    float scG[3] = { 0.f, 0.f, 0.f };   // combined dequant rowmax/(127*127)
    #pragma unroll
    for (int g = 0; g < 3; ++g) {
        #pragma unroll
        for (int i = 0; i < 2; ++i) {
            const float* wr = W_hh + (size_t)(g * 256 + wv * 32 + i * 16 + colL) * HH;
            float m = 0.f;
            #pragma unroll
            for (int kt = 0; kt < 4; ++kt)
                #pragma unroll
                for (int u4 = 0; u4 < 4; ++u4) {
                    float4 v = *(const float4*)(wr + kt * 64 + quad * 16 + u4 * 4);
                    m = fmaxf(m, fmaxf(fmaxf(fabsf(v.x), fabsf(v.y)),
                                       fmaxf(fabsf(v.z), fabsf(v.w))));
                }
            m = fmaxf(m, __shfl_xor(m, 16));    // full row spans all 4 quads
            m = fmaxf(m, __shfl_xor(m, 32));
            float inv = m > 1e-30f ? 127.f / m : 0.f;
            float sc  = m * (1.f / 16129.f);
            #pragma unroll
            for (int kt = 0; kt < 4; ++kt) {
                int pk[4];
                #pragma unroll
                for (int u4 = 0; u4 < 4; ++u4) {
                    float4 v = *(const float4*)(wr + kt * 64 + quad * 16 + u4 * 4);
                    int q0 = (int)rintf(fminf(fmaxf(v.x * inv, -127.f), 127.f));
                    int q1 = (int)rintf(fminf(fmaxf(v.y * inv, -127.f), 127.f));
                    int q2 = (int)rintf(fminf(fmaxf(v.z * inv, -127.f), 127.f));
                    int q3 = (int)rintf(fminf(fmaxf(v.w * inv, -127.f), 127.f));
                    pk[u4] = (q0 & 255) | ((q1 & 255) << 8) | ((q2 & 255) << 16) | (q3 << 24);
                }
                i32x4 t = { pk[0], pk[1], pk[2], pk[3] };
                Bq[g][i][kt] = t;
            }
            if (i == i16) scG[g] = sc;
        }
    }

    float hreg = (t0 == 0) ? 0.f : hstate[b * HH + j];
    if (lane < 32) {
        float hc = fminf(fmaxf(hreg, -1.f), 1.f);
        ((char*)hqBuf[0])[j] = (char)(int)rintf(hc * 127.f);
    }
    const float bhn = b_hh[512 + j];
    const u16* xgb = xgw;
    float* outb = out + (size_t)b * TT * HH;

    // 2-deep xg prefetch (upper half-wave duplicates lower -> same cachelines)
    float pr0 = bf2f(xgb[j]),      pz0 = bf2f(xgb[256 + j]),      pn0 = bf2f(xgb[512 + j]);
    float pr1 = bf2f(xgb[G3 + j]), pz1 = bf2f(xgb[G3 + 256 + j]), pn1 = bf2f(xgb[G3 + 512 + j]);
    __syncthreads();   // once: weight/h init visible

    for (int tc = 0; tc < Tc; tc += 2) {
        GRU_STEP(tc,     hqBuf[0], hqBuf[1], pr0, pz0, pn0);
        GRU_STEP(tc + 1, hqBuf[1], hqBuf[0], pr1, pz1, pn1);
    }

    if (t0 + Tc < TT && lane < 32)      // only needed across chunks
        hstate[b * HH + j] = hreg;
}

extern "C" void kernel_launch(void* const* d_in, const int* in_sizes, int n_in,
                              void* d_out, int out_size, void* d_ws, size_t ws_size,
                              hipStream_t stream) {
    const float* x    = (const float*)d_in[0];
    const float* W_ih = (const float*)d_in[1];
    const float* W_hh = (const float*)d_in[2];
    const float* b_ih = (const float*)d_in[3];
    const float* b_hh = (const float*)d_in[4];
    float* out = (float*)d_out;                    // fp32 output [B,T,H]

    float* hstate = (float*)d_ws;                  // 256*256 fp32 = 256 KB
    u16* xg = (u16*)((char*)d_ws + 262144);        // [256*Tc, 768] bf16
    size_t avail = ws_size > 262144 ? ws_size - 262144 : 0;

    int Tc = TT;                                   // shrink chunk to fit ws
    while (Tc > 16 && (size_t)256 * Tc * G3 * 2 > avail) Tc >>= 1;

    for (int t0 = 0; t0 < TT; t0 += Tc) {
        gru_fused<<<dim3(256), 512, 0, stream>>>(
            x, W_ih, W_hh, b_ih, b_hh, xg, out, hstate, t0, Tc);
    }
}